// Round 5
// baseline (478.563 us; speedup 1.0000x reference)
//
#include <hip/hip_runtime.h>
#include <math.h>

#define NTOK 65536
#define DIMD 128
#define KCB  2048

typedef unsigned short u16;
typedef __attribute__((ext_vector_type(8))) unsigned short u16x8;
typedef __attribute__((ext_vector_type(8))) __bf16 bf16x8;
typedef __attribute__((ext_vector_type(4))) float f32x4;

union U8 { u16x8 u; bf16x8 b; };

__device__ __forceinline__ u16 f2bf(float f) {
  union { float f; unsigned u; } c; c.f = f;
  unsigned r = c.u + 0x7FFFu + ((c.u >> 16) & 1u);
  return (u16)(r >> 16);
}
__device__ __forceinline__ float bf2f(u16 h) {
  union { unsigned u; float f; } c; c.u = ((unsigned)h) << 16;
  return c.f;
}

__device__ __forceinline__ float block_reduce4(float v, volatile float* sm, int tid) {
  #pragma unroll
  for (int off = 32; off; off >>= 1) v += __shfl_xor(v, off, 64);
  __syncthreads();
  if ((tid & 63) == 0) sm[tid >> 6] = v;
  __syncthreads();
  float r = sm[0] + sm[1] + sm[2] + sm[3];
  __syncthreads();
  return r;
}

// issue 8 global_load_lds (16B) staging one 64-code half (H+L) -- vmcnt +8
__device__ __forceinline__ void stage_half(const char* srcH, const char* srcL, char* ldsBase) {
  #pragma unroll
  for (int i = 0; i < 4; ++i) {
    __builtin_amdgcn_global_load_lds((const __attribute__((address_space(1))) void*)(srcH + i * 4096),
                                     (__attribute__((address_space(3))) void*)(ldsBase + i * 4096), 16, 0, 0);
    __builtin_amdgcn_global_load_lds((const __attribute__((address_space(1))) void*)(srcL + i * 4096),
                                     (__attribute__((address_space(3))) void*)(ldsBase + 16384 + i * 4096), 16, 0, 0);
  }
}

// ---------------- small kernels ----------------

__global__ __launch_bounds__(256) void k_zero(float* __restrict__ avgp, float* __restrict__ t1,
                                              float* __restrict__ acc3, float* __restrict__ cnt,
                                              int* __restrict__ wcount) {
  const int i = blockIdx.x * 256 + threadIdx.x;
  if (i < KCB) { avgp[i] = 0.0f; cnt[i] = 0.0f; }
  if (i == 0) { t1[0] = 0.0f; acc3[0] = 0.0f; acc3[1] = 0.0f; acc3[2] = 0.0f; wcount[0] = 0; }
}

__global__ __launch_bounds__(256) void k_prepx(const float* __restrict__ x, const float* __restrict__ mask,
                                               float* __restrict__ scaleInv, u16* __restrict__ xh,
                                               u16* __restrict__ xl) {
  const int wid = (blockIdx.x * 256 + threadIdx.x) >> 6;
  const int lane = threadIdx.x & 63;
  if (wid >= NTOK) return;
  const float add = (1.0f - mask[wid]) * 1e-6f;
  const float2 v = *(const float2*)(x + (size_t)wid * DIMD + lane * 2);
  const float a0 = v.x + add, a1 = v.y + add;
  float ss = a0 * a0 + a1 * a1;
  #pragma unroll
  for (int off = 32; off; off >>= 1) ss += __shfl_xor(ss, off, 64);
  const float sc = 1.0f / fmaxf(sqrtf(ss), 1e-6f);
  if (lane == 0) scaleInv[wid] = sc;
  const float f0 = a0 * sc, f1 = a1 * sc;
  const u16 h0 = f2bf(f0), h1 = f2bf(f1);
  const u16 g0 = f2bf(f0 - bf2f(h0)), g1 = f2bf(f1 - bf2f(h1));
  union { u16 s[2]; unsigned u; } wh, wl;
  wh.s[0] = h0; wh.s[1] = h1; wl.s[0] = g0; wl.s[1] = g1;
  *(unsigned*)(xh + (size_t)wid * DIMD + lane * 2) = wh.u;
  *(unsigned*)(xl + (size_t)wid * DIMD + lane * 2) = wl.u;
}

__global__ __launch_bounds__(256) void k_splitcb(const float* __restrict__ cb, u16* __restrict__ cbh,
                                                 u16* __restrict__ cbl) {
  const int wid = (blockIdx.x * 256 + threadIdx.x) >> 6;
  const int lane = threadIdx.x & 63;
  if (wid >= KCB) return;
  const float2 v = *(const float2*)(cb + (size_t)wid * DIMD + lane * 2);
  const u16 h0 = f2bf(v.x), h1 = f2bf(v.y);
  const u16 g0 = f2bf(v.x - bf2f(h0)), g1 = f2bf(v.y - bf2f(h1));
  union { u16 s[2]; unsigned u; } wh, wl;
  wh.s[0] = h0; wh.s[1] = h1; wl.s[0] = g0; wl.s[1] = g1;
  *(unsigned*)(cbh + (size_t)wid * DIMD + lane * 2) = wh.u;
  *(unsigned*)(cbl + (size_t)wid * DIMD + lane * 2) = wl.u;
}

__global__ __launch_bounds__(256) void k_gather(const float* __restrict__ cb, const float* __restrict__ mask,
                                                const int* __restrict__ rowIdx, float* __restrict__ outQ,
                                                float* __restrict__ outCnt, float* __restrict__ outEnc) {
  const int g = blockIdx.x * 256 + threadIdx.x;
  const int row = g >> 5, l = g & 31;
  if (row >= NTOK) return;
  const int idx = rowIdx[row];
  const float4 v = *(const float4*)(cb + (size_t)idx * DIMD + l * 4);
  *(float4*)(outQ + (size_t)row * DIMD + l * 4) = v;
  if (l == 0) {
    atomicAdd(&outCnt[idx], mask[row]);
    outEnc[row] = (float)idx;
  }
}

// build compacted worklist of near-tie rows
__global__ __launch_bounds__(256) void k_flag(const float* __restrict__ rowV1, const float* __restrict__ rowV2,
                                              int* __restrict__ wlist, int* __restrict__ wcount) {
  const int n = blockIdx.x * 256 + threadIdx.x;
  if (n >= NTOK) return;
  if (rowV1[n] - rowV2[n] <= 1e-4f) {
    const int p = atomicAdd(wcount, 1);
    wlist[p] = n;
  }
}

// exact-f32 argmax for worklist rows: block per row, x in LDS (broadcast), threads over k
__global__ __launch_bounds__(256) void k_refine2(const float* __restrict__ x, const float* __restrict__ mask,
                                                 const float* __restrict__ cb, const float* __restrict__ scaleInv,
                                                 const int* __restrict__ wlist, const int* __restrict__ wcount,
                                                 int* __restrict__ rowIdx) {
  __shared__ __align__(16) float xs[DIMD];
  __shared__ float sbv[4];
  __shared__ int sbi[4];
  const int tid = threadIdx.x;
  const int cnt = wcount[0];
  for (int j = blockIdx.x; j < cnt; j += gridDim.x) {
    const int row = wlist[j];
    __syncthreads();  // protect xs reuse across worklist iterations
    if (tid < 32) {
      const float add = (1.0f - mask[row]) * 1e-6f;
      const float sc = scaleInv[row];
      float4 t = ((const float4*)(x + (size_t)row * DIMD))[tid];
      t.x = (t.x + add) * sc; t.y = (t.y + add) * sc;
      t.z = (t.z + add) * sc; t.w = (t.w + add) * sc;
      ((float4*)xs)[tid] = t;
    }
    __syncthreads();
    float best = -1e30f;
    int bidx = 0x7fffffff;
    #pragma unroll
    for (int i = 0; i < 8; ++i) {
      const int k = i * 256 + tid;
      const float4* crow = (const float4*)(cb + (size_t)k * DIMD);
      float d0 = 0.f, d1 = 0.f;
      #pragma unroll
      for (int q = 0; q < 32; q += 2) {
        const float4 c0 = crow[q], c1 = crow[q + 1];
        const float4 x0 = ((const float4*)xs)[q], x1 = ((const float4*)xs)[q + 1];
        d0 = fmaf(c0.x, x0.x, d0); d0 = fmaf(c0.y, x0.y, d0);
        d0 = fmaf(c0.z, x0.z, d0); d0 = fmaf(c0.w, x0.w, d0);
        d1 = fmaf(c1.x, x1.x, d1); d1 = fmaf(c1.y, x1.y, d1);
        d1 = fmaf(c1.z, x1.z, d1); d1 = fmaf(c1.w, x1.w, d1);
      }
      const float d = d0 + d1;
      if (d > best || (d == best && k < bidx)) { best = d; bidx = k; }
    }
    #pragma unroll
    for (int off = 32; off; off >>= 1) {
      const float ob = __shfl_xor(best, off, 64);
      const int oi = __shfl_xor(bidx, off, 64);
      if (ob > best || (ob == best && oi < bidx)) { best = ob; bidx = oi; }
    }
    if ((tid & 63) == 0) { sbv[tid >> 6] = best; sbi[tid >> 6] = bidx; }
    __syncthreads();
    if (tid == 0) {
      float b = sbv[0]; int bi = sbi[0];
      #pragma unroll
      for (int w2 = 1; w2 < 4; ++w2)
        if (sbv[w2] > b || (sbv[w2] == b && sbi[w2] < bi)) { b = sbv[w2]; bi = sbi[w2]; }
      rowIdx[row] = bi;
    }
  }
}

// ---------------- MFMA pass 1: per-row max / argmax(top2) / Z ----------------

__global__ __launch_bounds__(256, 2) void k_pass1(const u16* __restrict__ xh, const u16* __restrict__ xl,
                                                  const u16* __restrict__ cbh, const u16* __restrict__ cbl,
                                                  float* __restrict__ rowV1, float* __restrict__ rowZ,
                                                  float* __restrict__ rowV2, int* __restrict__ rowIdx) {
  __shared__ __align__(16) char Bsmem[65536];  // 2 half-buffers x (16KB H + 16KB L)
  const int tid = threadIdx.x;
  const int lane = tid & 63, w = tid >> 6;
  const int l15 = lane & 15, hi = lane >> 4;
  const int row0 = blockIdx.x * 128;

  const int tbase = ((tid >> 4) << 8) + ((((tid & 15) << 4)) ^ (((tid >> 4) & 7) << 4));
  const char* cbh_c = (const char*)cbh;
  const char* cbl_c = (const char*)cbl;

  U8 Ah[2][4], Al[2][4];
  #pragma unroll
  for (int mf = 0; mf < 2; ++mf) {
    const size_t arow = (size_t)(row0 + w * 32 + mf * 16 + l15);
    #pragma unroll
    for (int ks = 0; ks < 4; ++ks) {
      const size_t off = arow * DIMD + ks * 32 + hi * 8;
      Ah[mf][ks].u = *(const u16x8*)(xh + off);
      Al[mf][ks].u = *(const u16x8*)(xl + off);
    }
  }
  const int laneAB = l15 * 256;
  int koff[4];
  #pragma unroll
  for (int ks = 0; ks < 4; ++ks) koff[ks] = (ks * 64 + hi * 16) ^ ((l15 & 7) << 4);

  float v1[8], v2[8], rs[8];
  int k1[8];
  #pragma unroll
  for (int r = 0; r < 8; ++r) { v1[r] = -1e30f; v2[r] = -1e30f; rs[r] = 0.0f; k1[r] = 0; }

  stage_half(cbh_c + 0 * 16384 + tbase, cbl_c + 0 * 16384 + tbase, Bsmem + 0 * 32768 + w * 1024);
  stage_half(cbh_c + 1 * 16384 + tbase, cbl_c + 1 * 16384 + tbase, Bsmem + 1 * 32768 + w * 1024);

  #pragma unroll 2
  for (int t = 0; t < 32; ++t) {
    const int b = t & 1;
    if (t < 30) asm volatile("s_waitcnt vmcnt(8)" ::: "memory");
    else        asm volatile("s_waitcnt vmcnt(0)" ::: "memory");
    __builtin_amdgcn_sched_barrier(0);
    __builtin_amdgcn_s_barrier();
    __builtin_amdgcn_sched_barrier(0);

    const char* base = Bsmem + b * 32768;
    f32x4 acc[2][4];
    #pragma unroll
    for (int m = 0; m < 2; ++m)
      #pragma unroll
      for (int nf = 0; nf < 4; ++nf) acc[m][nf] = (f32x4){0.f, 0.f, 0.f, 0.f};

    __builtin_amdgcn_s_setprio(1);
    #pragma unroll
    for (int ks = 0; ks < 4; ++ks) {
      const char* pH = base + laneAB + koff[ks];
      const char* pL = pH + 16384;
      #pragma unroll
      for (int nf = 0; nf < 4; ++nf) {
        U8 bh, bl;
        bh.u = *(const u16x8*)(pH + nf * 4096);
        bl.u = *(const u16x8*)(pL + nf * 4096);
        acc[0][nf] = __builtin_amdgcn_mfma_f32_16x16x32_bf16(Ah[0][ks].b, bh.b, acc[0][nf], 0, 0, 0);
        acc[1][nf] = __builtin_amdgcn_mfma_f32_16x16x32_bf16(Ah[1][ks].b, bh.b, acc[1][nf], 0, 0, 0);
        acc[0][nf] = __builtin_amdgcn_mfma_f32_16x16x32_bf16(Al[0][ks].b, bh.b, acc[0][nf], 0, 0, 0);
        acc[1][nf] = __builtin_amdgcn_mfma_f32_16x16x32_bf16(Al[1][ks].b, bh.b, acc[1][nf], 0, 0, 0);
        acc[0][nf] = __builtin_amdgcn_mfma_f32_16x16x32_bf16(Ah[0][ks].b, bl.b, acc[0][nf], 0, 0, 0);
        acc[1][nf] = __builtin_amdgcn_mfma_f32_16x16x32_bf16(Ah[1][ks].b, bl.b, acc[1][nf], 0, 0, 0);
      }
    }
    __builtin_amdgcn_s_setprio(0);
    asm volatile("s_waitcnt lgkmcnt(0)" ::: "memory");
    __builtin_amdgcn_sched_barrier(0);
    __builtin_amdgcn_s_barrier();
    __builtin_amdgcn_sched_barrier(0);
    if (t < 30)
      stage_half(cbh_c + (size_t)(t + 2) * 16384 + tbase, cbl_c + (size_t)(t + 2) * 16384 + tbase,
                 Bsmem + b * 32768 + w * 1024);

    // epilogue (registers only) overlaps the prefetch
    const int colbase = t * 64 + l15;
    #pragma unroll
    for (int m = 0; m < 2; ++m)
      #pragma unroll
      for (int rg = 0; rg < 4; ++rg) {
        const int r = m * 4 + rg;
        float vv1 = v1[r], vv2 = v2[r];
        int kk1 = k1[r];
        const float mold = vv1;
        #pragma unroll
        for (int nf = 0; nf < 4; ++nf) {
          const float xv = acc[m][nf][rg];
          const int kk = colbase + nf * 16;
          const bool bb = xv > vv1;
          vv2 = bb ? vv1 : fmaxf(vv2, xv);
          kk1 = bb ? kk : kk1;
          vv1 = bb ? xv : vv1;
        }
        const float m200 = vv1 * 200.f;
        float z = rs[r] * __expf(fmaf(mold, 200.f, -m200));
        #pragma unroll
        for (int nf = 0; nf < 4; ++nf)
          z += __expf(fmaf(acc[m][nf][rg], 200.f, -m200));
        v1[r] = vv1; v2[r] = vv2; k1[r] = kk1; rs[r] = z;
      }
  }

  #pragma unroll
  for (int m = 0; m < 2; ++m)
    #pragma unroll
    for (int rg = 0; rg < 4; ++rg) {
      const int r = m * 4 + rg;
      float a1 = v1[r], a2 = v2[r], az = rs[r];
      int ak = k1[r];
      #pragma unroll
      for (int off = 1; off <= 8; off <<= 1) {
        const float o1 = __shfl_xor(a1, off, 64);
        const float o2 = __shfl_xor(a2, off, 64);
        const float oz = __shfl_xor(az, off, 64);
        const int okk = __shfl_xor(ak, off, 64);
        const float nm = fmaxf(a1, o1);
        az = az * __expf((a1 - nm) * 200.f) + oz * __expf((o1 - nm) * 200.f);
        a2 = fmaxf(fminf(a1, o1), fmaxf(a2, o2));
        const bool take = (o1 > a1) || (o1 == a1 && okk < ak);
        ak = take ? okk : ak;
        a1 = nm;
      }
      if (l15 == 0) {
        const int row = row0 + w * 32 + m * 16 + hi * 4 + rg;
        rowV1[row] = a1; rowZ[row] = az; rowV2[row] = a2; rowIdx[row] = ak;
      }
    }
}

// ---------------- MFMA pass 2: avg_probs column sums + sample-entropy ----------------

__global__ __launch_bounds__(256, 2) void k_pass2(const u16* __restrict__ xh, const u16* __restrict__ xl,
                                                  const u16* __restrict__ cbh, const u16* __restrict__ cbl,
                                                  const float* __restrict__ mask, const float* __restrict__ rowV1,
                                                  const float* __restrict__ rowZ, float* __restrict__ avgp,
                                                  float* __restrict__ t1g) {
  __shared__ __align__(16) char Bsmem[65536];
  __shared__ float ap[KCB];
  __shared__ float sm4[4];
  const int tid = threadIdx.x;
  const int lane = tid & 63, w = tid >> 6;
  const int l15 = lane & 15, hi = lane >> 4;
  const int row0 = blockIdx.x * 128;

  for (int i = tid; i < KCB; i += 256) ap[i] = 0.0f;

  const int tbase = ((tid >> 4) << 8) + ((((tid & 15) << 4)) ^ (((tid >> 4) & 7) << 4));
  const char* cbh_c = (const char*)cbh;
  const char* cbl_c = (const char*)cbl;

  U8 Ah[2][4], Al[2][4];
  #pragma unroll
  for (int mf = 0; mf < 2; ++mf) {
    const size_t arow = (size_t)(row0 + w * 32 + mf * 16 + l15);
    #pragma unroll
    for (int ks = 0; ks < 4; ++ks) {
      const size_t off = arow * DIMD + ks * 32 + hi * 8;
      Ah[mf][ks].u = *(const u16x8*)(xh + off);
      Al[mf][ks].u = *(const u16x8*)(xl + off);
    }
  }
  const int laneAB = l15 * 256;
  int koff[4];
  #pragma unroll
  for (int ks = 0; ks < 4; ++ks) koff[ks] = (ks * 64 + hi * 16) ^ ((l15 & 7) << 4);

  // offr = log(mask/Z) - 200*max  => p_masked = exp(200*s + offr); t1' = sum p*u'
  float offr[8];
  #pragma unroll
  for (int m = 0; m < 2; ++m)
    #pragma unroll
    for (int rg = 0; rg < 4; ++rg) {
      const int r = m * 4 + rg;
      const int row = row0 + w * 32 + m * 16 + hi * 4 + rg;
      const float zim = mask[row] / rowZ[row];
      const float lz = (zim > 0.0f) ? __logf(zim) : -1e30f;
      offr[r] = lz - 200.f * rowV1[row];
    }
  float t1 = 0.0f;

  stage_half(cbh_c + 0 * 16384 + tbase, cbl_c + 0 * 16384 + tbase, Bsmem + 0 * 32768 + w * 1024);
  stage_half(cbh_c + 1 * 16384 + tbase, cbl_c + 1 * 16384 + tbase, Bsmem + 1 * 32768 + w * 1024);

  // one barrier so the ap[] zeroing is visible before any wave's epilogue atomics
  __builtin_amdgcn_s_barrier();

  #pragma unroll 2
  for (int t = 0; t < 32; ++t) {
    const int b = t & 1;
    if (t < 30) asm volatile("s_waitcnt vmcnt(8)" ::: "memory");
    else        asm volatile("s_waitcnt vmcnt(0)" ::: "memory");
    __builtin_amdgcn_sched_barrier(0);
    __builtin_amdgcn_s_barrier();
    __builtin_amdgcn_sched_barrier(0);

    const char* base = Bsmem + b * 32768;
    f32x4 acc[2][4];
    #pragma unroll
    for (int m = 0; m < 2; ++m)
      #pragma unroll
      for (int nf = 0; nf < 4; ++nf) acc[m][nf] = (f32x4){0.f, 0.f, 0.f, 0.f};

    __builtin_amdgcn_s_setprio(1);
    #pragma unroll
    for (int ks = 0; ks < 4; ++ks) {
      const char* pH = base + laneAB + koff[ks];
      const char* pL = pH + 16384;
      #pragma unroll
      for (int nf = 0; nf < 4; ++nf) {
        U8 bh, bl;
        bh.u = *(const u16x8*)(pH + nf * 4096);
        bl.u = *(const u16x8*)(pL + nf * 4096);
        acc[0][nf] = __builtin_amdgcn_mfma_f32_16x16x32_bf16(Ah[0][ks].b, bh.b, acc[0][nf], 0, 0, 0);
        acc[1][nf] = __builtin_amdgcn_mfma_f32_16x16x32_bf16(Ah[1][ks].b, bh.b, acc[1][nf], 0, 0, 0);
        acc[0][nf] = __builtin_amdgcn_mfma_f32_16x16x32_bf16(Al[0][ks].b, bh.b, acc[0][nf], 0, 0, 0);
        acc[1][nf] = __builtin_amdgcn_mfma_f32_16x16x32_bf16(Al[1][ks].b, bh.b, acc[1][nf], 0, 0, 0);
        acc[0][nf] = __builtin_amdgcn_mfma_f32_16x16x32_bf16(Ah[0][ks].b, bl.b, acc[0][nf], 0, 0, 0);
        acc[1][nf] = __builtin_amdgcn_mfma_f32_16x16x32_bf16(Ah[1][ks].b, bl.b, acc[1][nf], 0, 0, 0);
      }
    }
    __builtin_amdgcn_s_setprio(0);
    asm volatile("s_waitcnt lgkmcnt(0)" ::: "memory");
    __builtin_amdgcn_sched_barrier(0);
    __builtin_amdgcn_s_barrier();
    __builtin_amdgcn_sched_barrier(0);
    if (t < 30)
      stage_half(cbh_c + (size_t)(t + 2) * 16384 + tbase, cbl_c + (size_t)(t + 2) * 16384 + tbase,
                 Bsmem + b * 32768 + w * 1024);

    float colsum[4];
    #pragma unroll
    for (int nf = 0; nf < 4; ++nf) colsum[nf] = 0.0f;
    #pragma unroll
    for (int m = 0; m < 2; ++m)
      #pragma unroll
      for (int rg = 0; rg < 4; ++rg) {
        const int r = m * 4 + rg;
        #pragma unroll
        for (int nf = 0; nf < 4; ++nf) {
          const float up = fmaf(acc[m][nf][rg], 200.f, offr[r]);
          const float p = __expf(up);
          colsum[nf] += p;
          t1 = fmaf(p, up, t1);
        }
      }
    #pragma unroll
    for (int nf = 0; nf < 4; ++nf) {
      colsum[nf] += __shfl_xor(colsum[nf], 16, 64);
      colsum[nf] += __shfl_xor(colsum[nf], 32, 64);
    }
    if (lane < 16) {
      #pragma unroll
      for (int nf = 0; nf < 4; ++nf)
        atomicAdd(&ap[t * 64 + nf * 16 + lane], colsum[nf]);
    }
  }

  __syncthreads();
  for (int i = tid; i < KCB; i += 256) atomicAdd(&avgp[i], ap[i]);
  #pragma unroll
  for (int off = 32; off; off >>= 1) t1 += __shfl_xor(t1, off, 64);
  if ((tid & 63) == 0) sm4[tid >> 6] = t1;
  __syncthreads();
  if (tid == 0) atomicAdd(t1g, sm4[0] + sm4[1] + sm4[2] + sm4[3]);
}

// ---------------- scalar reductions ----------------

__global__ __launch_bounds__(256) void k_stats(const float* __restrict__ mask, const float* __restrict__ rowV1,
                                               float* __restrict__ acc3) {
  __shared__ float sm[4];
  const int tid = threadIdx.x;
  float msum = 0.f, slat = 0.f;
  for (int n = blockIdx.x * 256 + tid; n < NTOK; n += gridDim.x * 256) {
    const float mk = mask[n];
    msum += mk;
    slat = fmaf(mk, 2.0f - 2.0f * rowV1[n], slat);
  }
  msum = block_reduce4(msum, sm, tid);
  slat = block_reduce4(slat, sm, tid);
  if (tid == 0) {
    atomicAdd(&acc3[0], msum);
    atomicAdd(&acc3[1], slat);
  }
}

__global__ __launch_bounds__(256) void k_final(const float* __restrict__ avgp, const float* __restrict__ t1g,
                                               const float* __restrict__ acc3, float* __restrict__ out3) {
  __shared__ float sm[4];
  const int tid = threadIdx.x;
  const float msum = acc3[0];
  float ae = 0.f;
  for (int k2 = tid; k2 < KCB; k2 += 256) {
    const float a = avgp[k2] / msum;
    ae += a * __logf(a + 1e-5f);
  }
  ae = block_reduce4(ae, sm, tid);
  if (tid == 0) {
    const float sample_entropy = -t1g[0] / msum;  // slogz folded analytically
    const float lat = acc3[1] / (msum + 1e-6f);
    out3[0] = lat;
    out3[1] = lat;
    out3[2] = sample_entropy + ae;
  }
}

// ---------------- launcher ----------------

extern "C" void kernel_launch(void* const* d_in, const int* in_sizes, int n_in,
                              void* d_out, int out_size, void* d_ws, size_t ws_size,
                              hipStream_t stream) {
  const float* x = (const float*)d_in[0];
  const float* mask = (const float*)d_in[1];
  const float* cb = (const float*)d_in[2];

  float* out = (float*)d_out;
  float* outQ = out;
  float* out3 = out + (size_t)NTOK * DIMD;
  float* outCnt = out3 + 3;
  float* outEnc = outCnt + KCB;

  // bf16-split x lives in the quantized output region until k_gather overwrites it
  u16* xh = (u16*)outQ;
  u16* xl = xh + (size_t)NTOK * DIMD;

  float* ws = (float*)d_ws;
  float* scaleInv = ws;                        // N
  float* rowV1 = ws + NTOK;                    // N
  float* rowZ = ws + 2 * (size_t)NTOK;         // N
  float* rowV2 = ws + 3 * (size_t)NTOK;        // N
  int* rowIdx = (int*)(ws + 4 * (size_t)NTOK); // N
  float* avgp = ws + 5 * (size_t)NTOK;         // K
  float* t1g = avgp + KCB;                     // 1
  float* acc3 = t1g + 1;                       // 3
  u16* cbh = (u16*)(ws + 5 * (size_t)NTOK + KCB + 8);
  u16* cbl = cbh + (size_t)KCB * DIMD;
  int* wlist = (int*)(cbl + (size_t)KCB * DIMD);  // N ints
  int* wcount = wlist + NTOK;                     // 1

  k_zero<<<(KCB + 255) / 256, 256, 0, stream>>>(avgp, t1g, acc3, outCnt, wcount);
  k_prepx<<<(NTOK * 64) / 256, 256, 0, stream>>>(x, mask, scaleInv, xh, xl);
  k_splitcb<<<(KCB * 64) / 256, 256, 0, stream>>>(cb, cbh, cbl);
  k_pass1<<<NTOK / 128, 256, 0, stream>>>(xh, xl, cbh, cbl, rowV1, rowZ, rowV2, rowIdx);
  k_flag<<<NTOK / 256, 256, 0, stream>>>(rowV1, rowV2, wlist, wcount);
  k_pass2<<<NTOK / 128, 256, 0, stream>>>(xh, xl, cbh, cbl, mask, rowV1, rowZ, avgp, t1g);
  k_stats<<<64, 256, 0, stream>>>(mask, rowV1, acc3);
  k_refine2<<<512, 256, 0, stream>>>(x, mask, cb, scaleInv, wlist, wcount, rowIdx);
  // gather runs after pass2 (outQ aliases xh/xl) and after refine2 (final rowIdx)
  k_gather<<<(NTOK * 32) / 256, 256, 0, stream>>>(cb, mask, rowIdx, outQ, outCnt, outEnc);
  k_final<<<1, 256, 0, stream>>>(avgp, t1g, acc3, out3);
}

// Round 6
// 267.062 us; speedup vs baseline: 1.7920x; 1.7920x over previous
//
#include <hip/hip_runtime.h>
#include <math.h>

#define NTOK 65536
#define DIMD 128
#define KCB  2048

typedef unsigned short u16;
typedef __attribute__((ext_vector_type(8))) unsigned short u16x8;
typedef __attribute__((ext_vector_type(8))) __bf16 bf16x8;
typedef __attribute__((ext_vector_type(4))) float f32x4;

union U8 { u16x8 u; bf16x8 b; };

__device__ __forceinline__ u16 f2bf(float f) {
  union { float f; unsigned u; } c; c.f = f;
  unsigned r = c.u + 0x7FFFu + ((c.u >> 16) & 1u);
  return (u16)(r >> 16);
}
__device__ __forceinline__ float bf2f(u16 h) {
  union { unsigned u; float f; } c; c.u = ((unsigned)h) << 16;
  return c.f;
}

__device__ __forceinline__ float block_reduce4(float v, volatile float* sm, int tid) {
  #pragma unroll
  for (int off = 32; off; off >>= 1) v += __shfl_xor(v, off, 64);
  __syncthreads();
  if ((tid & 63) == 0) sm[tid >> 6] = v;
  __syncthreads();
  float r = sm[0] + sm[1] + sm[2] + sm[3];
  __syncthreads();
  return r;
}

// issue 8 global_load_lds (16B) staging one 64-code half (H+L) -- vmcnt +8
__device__ __forceinline__ void stage_half(const char* srcH, const char* srcL, char* ldsBase) {
  #pragma unroll
  for (int i = 0; i < 4; ++i) {
    __builtin_amdgcn_global_load_lds((const __attribute__((address_space(1))) void*)(srcH + i * 4096),
                                     (__attribute__((address_space(3))) void*)(ldsBase + i * 4096), 16, 0, 0);
    __builtin_amdgcn_global_load_lds((const __attribute__((address_space(1))) void*)(srcL + i * 4096),
                                     (__attribute__((address_space(3))) void*)(ldsBase + 16384 + i * 4096), 16, 0, 0);
  }
}

// ---------------- small kernels ----------------

__global__ __launch_bounds__(256) void k_zero(float* __restrict__ avgp, float* __restrict__ t1,
                                              float* __restrict__ acc3, float* __restrict__ cnt) {
  const int i = blockIdx.x * 256 + threadIdx.x;
  if (i < KCB) { avgp[i] = 0.0f; cnt[i] = 0.0f; }
  if (i == 0) { t1[0] = 0.0f; acc3[0] = 0.0f; acc3[1] = 0.0f; acc3[2] = 0.0f; }
}

__global__ __launch_bounds__(256) void k_prepx(const float* __restrict__ x, const float* __restrict__ mask,
                                               u16* __restrict__ xh, u16* __restrict__ xl) {
  const int wid = (blockIdx.x * 256 + threadIdx.x) >> 6;
  const int lane = threadIdx.x & 63;
  if (wid >= NTOK) return;
  const float add = (1.0f - mask[wid]) * 1e-6f;
  const float2 v = *(const float2*)(x + (size_t)wid * DIMD + lane * 2);
  const float a0 = v.x + add, a1 = v.y + add;
  float ss = a0 * a0 + a1 * a1;
  #pragma unroll
  for (int off = 32; off; off >>= 1) ss += __shfl_xor(ss, off, 64);
  const float sc = 1.0f / fmaxf(sqrtf(ss), 1e-6f);
  const float f0 = a0 * sc, f1 = a1 * sc;
  const u16 h0 = f2bf(f0), h1 = f2bf(f1);
  const u16 g0 = f2bf(f0 - bf2f(h0)), g1 = f2bf(f1 - bf2f(h1));
  union { u16 s[2]; unsigned u; } wh, wl;
  wh.s[0] = h0; wh.s[1] = h1; wl.s[0] = g0; wl.s[1] = g1;
  *(unsigned*)(xh + (size_t)wid * DIMD + lane * 2) = wh.u;
  *(unsigned*)(xl + (size_t)wid * DIMD + lane * 2) = wl.u;
}

__global__ __launch_bounds__(256) void k_splitcb(const float* __restrict__ cb, u16* __restrict__ cbh,
                                                 u16* __restrict__ cbl) {
  const int wid = (blockIdx.x * 256 + threadIdx.x) >> 6;
  const int lane = threadIdx.x & 63;
  if (wid >= KCB) return;
  const float2 v = *(const float2*)(cb + (size_t)wid * DIMD + lane * 2);
  const u16 h0 = f2bf(v.x), h1 = f2bf(v.y);
  const u16 g0 = f2bf(v.x - bf2f(h0)), g1 = f2bf(v.y - bf2f(h1));
  union { u16 s[2]; unsigned u; } wh, wl;
  wh.s[0] = h0; wh.s[1] = h1; wl.s[0] = g0; wl.s[1] = g1;
  *(unsigned*)(cbh + (size_t)wid * DIMD + lane * 2) = wh.u;
  *(unsigned*)(cbl + (size_t)wid * DIMD + lane * 2) = wl.u;
}

__global__ __launch_bounds__(256) void k_gather(const float* __restrict__ cb, const float* __restrict__ mask,
                                                const int* __restrict__ rowIdx, float* __restrict__ outQ,
                                                float* __restrict__ outCnt, float* __restrict__ outEnc) {
  const int g = blockIdx.x * 256 + threadIdx.x;
  const int row = g >> 5, l = g & 31;
  if (row >= NTOK) return;
  const int idx = rowIdx[row];
  const float4 v = *(const float4*)(cb + (size_t)idx * DIMD + l * 4);
  *(float4*)(outQ + (size_t)row * DIMD + l * 4) = v;
  if (l == 0) {
    atomicAdd(&outCnt[idx], mask[row]);
    outEnc[row] = (float)idx;
  }
}

// ---------------- MFMA pass 1: per-row max / argmax / Z ----------------

__global__ __launch_bounds__(256, 2) void k_pass1(const u16* __restrict__ xh, const u16* __restrict__ xl,
                                                  const u16* __restrict__ cbh, const u16* __restrict__ cbl,
                                                  float* __restrict__ rowV1, float* __restrict__ rowZ,
                                                  int* __restrict__ rowIdx) {
  __shared__ __align__(16) char Bsmem[65536];  // 2 half-buffers x (16KB H + 16KB L)
  const int tid = threadIdx.x;
  const int lane = tid & 63, w = tid >> 6;
  const int l15 = lane & 15, hi = lane >> 4;
  const int row0 = blockIdx.x * 128;

  const int tbase = ((tid >> 4) << 8) + ((((tid & 15) << 4)) ^ (((tid >> 4) & 7) << 4));
  const char* cbh_c = (const char*)cbh;
  const char* cbl_c = (const char*)cbl;

  U8 Ah[2][4], Al[2][4];
  #pragma unroll
  for (int mf = 0; mf < 2; ++mf) {
    const size_t arow = (size_t)(row0 + w * 32 + mf * 16 + l15);
    #pragma unroll
    for (int ks = 0; ks < 4; ++ks) {
      const size_t off = arow * DIMD + ks * 32 + hi * 8;
      Ah[mf][ks].u = *(const u16x8*)(xh + off);
      Al[mf][ks].u = *(const u16x8*)(xl + off);
    }
  }
  const int laneAB = l15 * 256;
  int koff[4];
  #pragma unroll
  for (int ks = 0; ks < 4; ++ks) koff[ks] = (ks * 64 + hi * 16) ^ ((l15 & 7) << 4);

  float v1[8], rs[8];
  int k1[8];
  #pragma unroll
  for (int r = 0; r < 8; ++r) { v1[r] = -1e30f; rs[r] = 0.0f; k1[r] = 0; }

  stage_half(cbh_c + 0 * 16384 + tbase, cbl_c + 0 * 16384 + tbase, Bsmem + 0 * 32768 + w * 1024);
  stage_half(cbh_c + 1 * 16384 + tbase, cbl_c + 1 * 16384 + tbase, Bsmem + 1 * 32768 + w * 1024);

  #pragma unroll 2
  for (int t = 0; t < 32; ++t) {
    const int b = t & 1;
    if (t < 30) asm volatile("s_waitcnt vmcnt(8)" ::: "memory");
    else        asm volatile("s_waitcnt vmcnt(0)" ::: "memory");
    __builtin_amdgcn_sched_barrier(0);
    __builtin_amdgcn_s_barrier();
    __builtin_amdgcn_sched_barrier(0);

    const char* base = Bsmem + b * 32768;
    f32x4 acc[2][4];
    #pragma unroll
    for (int m = 0; m < 2; ++m)
      #pragma unroll
      for (int nf = 0; nf < 4; ++nf) acc[m][nf] = (f32x4){0.f, 0.f, 0.f, 0.f};

    __builtin_amdgcn_s_setprio(1);
    #pragma unroll
    for (int ks = 0; ks < 4; ++ks) {
      const char* pH = base + laneAB + koff[ks];
      const char* pL = pH + 16384;
      #pragma unroll
      for (int nf = 0; nf < 4; ++nf) {
        U8 bh, bl;
        bh.u = *(const u16x8*)(pH + nf * 4096);
        bl.u = *(const u16x8*)(pL + nf * 4096);
        acc[0][nf] = __builtin_amdgcn_mfma_f32_16x16x32_bf16(Ah[0][ks].b, bh.b, acc[0][nf], 0, 0, 0);
        acc[1][nf] = __builtin_amdgcn_mfma_f32_16x16x32_bf16(Ah[1][ks].b, bh.b, acc[1][nf], 0, 0, 0);
        acc[0][nf] = __builtin_amdgcn_mfma_f32_16x16x32_bf16(Al[0][ks].b, bh.b, acc[0][nf], 0, 0, 0);
        acc[1][nf] = __builtin_amdgcn_mfma_f32_16x16x32_bf16(Al[1][ks].b, bh.b, acc[1][nf], 0, 0, 0);
        acc[0][nf] = __builtin_amdgcn_mfma_f32_16x16x32_bf16(Ah[0][ks].b, bl.b, acc[0][nf], 0, 0, 0);
        acc[1][nf] = __builtin_amdgcn_mfma_f32_16x16x32_bf16(Ah[1][ks].b, bl.b, acc[1][nf], 0, 0, 0);
      }
    }
    __builtin_amdgcn_s_setprio(0);
    asm volatile("s_waitcnt lgkmcnt(0)" ::: "memory");
    __builtin_amdgcn_sched_barrier(0);
    __builtin_amdgcn_s_barrier();
    __builtin_amdgcn_sched_barrier(0);
    if (t < 30)
      stage_half(cbh_c + (size_t)(t + 2) * 16384 + tbase, cbl_c + (size_t)(t + 2) * 16384 + tbase,
                 Bsmem + b * 32768 + w * 1024);

    // epilogue (registers only) overlaps the prefetch
    const int colbase = t * 64 + l15;
    #pragma unroll
    for (int m = 0; m < 2; ++m)
      #pragma unroll
      for (int rg = 0; rg < 4; ++rg) {
        const int r = m * 4 + rg;
        float vv1 = v1[r];
        int kk1 = k1[r];
        const float mold = vv1;
        const float x0 = acc[m][0][rg], x1 = acc[m][1][rg];
        const float x2 = acc[m][2][rg], x3 = acc[m][3][rg];
        if (x0 > vv1) { vv1 = x0; kk1 = colbase; }
        if (x1 > vv1) { vv1 = x1; kk1 = colbase + 16; }
        if (x2 > vv1) { vv1 = x2; kk1 = colbase + 32; }
        if (x3 > vv1) { vv1 = x3; kk1 = colbase + 48; }
        const float mx = fmaxf(fmaxf(x0, x1), fmaxf(x2, x3));
        float z = rs[r];
        // rescale only if some lane's max moved (uniform branch; exp(0)=1 for others)
        if (__any(vv1 > mold)) z *= __expf(200.f * (mold - vv1));
        // skip the 4-exp sum when the whole row-group tile is negligible (uniform)
        if (__any(200.f * (mx - vv1) > -25.f)) {
          z += __expf(200.f * (x0 - vv1));
          z += __expf(200.f * (x1 - vv1));
          z += __expf(200.f * (x2 - vv1));
          z += __expf(200.f * (x3 - vv1));
        }
        v1[r] = vv1; k1[r] = kk1; rs[r] = z;
      }
  }

  // cross-lane merge within each 16-lane group
  #pragma unroll
  for (int m = 0; m < 2; ++m)
    #pragma unroll
    for (int rg = 0; rg < 4; ++rg) {
      const int r = m * 4 + rg;
      float a1 = v1[r], az = rs[r];
      int ak = k1[r];
      #pragma unroll
      for (int off = 1; off <= 8; off <<= 1) {
        const float o1 = __shfl_xor(a1, off, 64);
        const float oz = __shfl_xor(az, off, 64);
        const int okk = __shfl_xor(ak, off, 64);
        const float nm = fmaxf(a1, o1);
        az = az * __expf((a1 - nm) * 200.f) + oz * __expf((o1 - nm) * 200.f);
        const bool take = (o1 > a1) || (o1 == a1 && okk < ak);
        ak = take ? okk : ak;
        a1 = nm;
      }
      if (l15 == 0) {
        const int row = row0 + w * 32 + m * 16 + hi * 4 + rg;
        rowV1[row] = a1; rowZ[row] = az; rowIdx[row] = ak;
      }
    }
}

// ---------------- MFMA pass 2: avg_probs column sums + sample-entropy ----------------

__global__ __launch_bounds__(256, 2) void k_pass2(const u16* __restrict__ xh, const u16* __restrict__ xl,
                                                  const u16* __restrict__ cbh, const u16* __restrict__ cbl,
                                                  const float* __restrict__ mask, const float* __restrict__ rowV1,
                                                  const float* __restrict__ rowZ, float* __restrict__ avgp,
                                                  float* __restrict__ t1g) {
  __shared__ __align__(16) char Bsmem[65536];
  __shared__ float ap[KCB];
  __shared__ float sm4[4];
  const int tid = threadIdx.x;
  const int lane = tid & 63, w = tid >> 6;
  const int l15 = lane & 15, hi = lane >> 4;
  const int row0 = blockIdx.x * 128;

  for (int i = tid; i < KCB; i += 256) ap[i] = 0.0f;

  const int tbase = ((tid >> 4) << 8) + ((((tid & 15) << 4)) ^ (((tid >> 4) & 7) << 4));
  const char* cbh_c = (const char*)cbh;
  const char* cbl_c = (const char*)cbl;

  U8 Ah[2][4], Al[2][4];
  #pragma unroll
  for (int mf = 0; mf < 2; ++mf) {
    const size_t arow = (size_t)(row0 + w * 32 + mf * 16 + l15);
    #pragma unroll
    for (int ks = 0; ks < 4; ++ks) {
      const size_t off = arow * DIMD + ks * 32 + hi * 8;
      Ah[mf][ks].u = *(const u16x8*)(xh + off);
      Al[mf][ks].u = *(const u16x8*)(xl + off);
    }
  }
  const int laneAB = l15 * 256;
  int koff[4];
  #pragma unroll
  for (int ks = 0; ks < 4; ++ks) koff[ks] = (ks * 64 + hi * 16) ^ ((l15 & 7) << 4);

  // offr = log(mask/Z) - 200*max  => p_masked = exp(200*s + offr); t1' = sum p*u'
  float offr[8];
  #pragma unroll
  for (int m = 0; m < 2; ++m)
    #pragma unroll
    for (int rg = 0; rg < 4; ++rg) {
      const int r = m * 4 + rg;
      const int row = row0 + w * 32 + m * 16 + hi * 4 + rg;
      const float zim = mask[row] / rowZ[row];
      const float lz = (zim > 0.0f) ? __logf(zim) : -1e30f;
      offr[r] = lz - 200.f * rowV1[row];
    }
  float t1 = 0.0f;

  stage_half(cbh_c + 0 * 16384 + tbase, cbl_c + 0 * 16384 + tbase, Bsmem + 0 * 32768 + w * 1024);
  stage_half(cbh_c + 1 * 16384 + tbase, cbl_c + 1 * 16384 + tbase, Bsmem + 1 * 32768 + w * 1024);

  // one barrier so the ap[] zeroing is visible before any wave's epilogue atomics
  __builtin_amdgcn_s_barrier();

  #pragma unroll 2
  for (int t = 0; t < 32; ++t) {
    const int b = t & 1;
    if (t < 30) asm volatile("s_waitcnt vmcnt(8)" ::: "memory");
    else        asm volatile("s_waitcnt vmcnt(0)" ::: "memory");
    __builtin_amdgcn_sched_barrier(0);
    __builtin_amdgcn_s_barrier();
    __builtin_amdgcn_sched_barrier(0);

    const char* base = Bsmem + b * 32768;
    f32x4 acc[2][4];
    #pragma unroll
    for (int m = 0; m < 2; ++m)
      #pragma unroll
      for (int nf = 0; nf < 4; ++nf) acc[m][nf] = (f32x4){0.f, 0.f, 0.f, 0.f};

    __builtin_amdgcn_s_setprio(1);
    #pragma unroll
    for (int ks = 0; ks < 4; ++ks) {
      const char* pH = base + laneAB + koff[ks];
      const char* pL = pH + 16384;
      #pragma unroll
      for (int nf = 0; nf < 4; ++nf) {
        U8 bh, bl;
        bh.u = *(const u16x8*)(pH + nf * 4096);
        bl.u = *(const u16x8*)(pL + nf * 4096);
        acc[0][nf] = __builtin_amdgcn_mfma_f32_16x16x32_bf16(Ah[0][ks].b, bh.b, acc[0][nf], 0, 0, 0);
        acc[1][nf] = __builtin_amdgcn_mfma_f32_16x16x32_bf16(Ah[1][ks].b, bh.b, acc[1][nf], 0, 0, 0);
        acc[0][nf] = __builtin_amdgcn_mfma_f32_16x16x32_bf16(Al[0][ks].b, bh.b, acc[0][nf], 0, 0, 0);
        acc[1][nf] = __builtin_amdgcn_mfma_f32_16x16x32_bf16(Al[1][ks].b, bh.b, acc[1][nf], 0, 0, 0);
        acc[0][nf] = __builtin_amdgcn_mfma_f32_16x16x32_bf16(Ah[0][ks].b, bl.b, acc[0][nf], 0, 0, 0);
        acc[1][nf] = __builtin_amdgcn_mfma_f32_16x16x32_bf16(Ah[1][ks].b, bl.b, acc[1][nf], 0, 0, 0);
      }
    }
    __builtin_amdgcn_s_setprio(0);
    asm volatile("s_waitcnt lgkmcnt(0)" ::: "memory");
    __builtin_amdgcn_sched_barrier(0);
    __builtin_amdgcn_s_barrier();
    __builtin_amdgcn_sched_barrier(0);
    if (t < 30)
      stage_half(cbh_c + (size_t)(t + 2) * 16384 + tbase, cbl_c + (size_t)(t + 2) * 16384 + tbase,
                 Bsmem + b * 32768 + w * 1024);

    float colsum[4];
    #pragma unroll
    for (int nf = 0; nf < 4; ++nf) colsum[nf] = 0.0f;
    #pragma unroll
    for (int m = 0; m < 2; ++m)
      #pragma unroll
      for (int rg = 0; rg < 4; ++rg) {
        const int r = m * 4 + rg;
        const float u0 = fmaf(acc[m][0][rg], 200.f, offr[r]);
        const float u1 = fmaf(acc[m][1][rg], 200.f, offr[r]);
        const float u2 = fmaf(acc[m][2][rg], 200.f, offr[r]);
        const float u3 = fmaf(acc[m][3][rg], 200.f, offr[r]);
        const float umx = fmaxf(fmaxf(u0, u1), fmaxf(u2, u3));
        // u <= 0 always; skip entire row-group tile when all probs < e^-25 (uniform)
        if (__any(umx > -25.f)) {
          const float p0 = __expf(u0), p1 = __expf(u1);
          const float p2 = __expf(u2), p3 = __expf(u3);
          colsum[0] += p0; colsum[1] += p1; colsum[2] += p2; colsum[3] += p3;
          t1 = fmaf(p0, u0, t1); t1 = fmaf(p1, u1, t1);
          t1 = fmaf(p2, u2, t1); t1 = fmaf(p3, u3, t1);
        }
      }
    #pragma unroll
    for (int nf = 0; nf < 4; ++nf) {
      colsum[nf] += __shfl_xor(colsum[nf], 16, 64);
      colsum[nf] += __shfl_xor(colsum[nf], 32, 64);
    }
    if (lane < 16) {
      #pragma unroll
      for (int nf = 0; nf < 4; ++nf)
        atomicAdd(&ap[t * 64 + nf * 16 + lane], colsum[nf]);
    }
  }

  __syncthreads();
  for (int i = tid; i < KCB; i += 256) atomicAdd(&avgp[i], ap[i]);
  #pragma unroll
  for (int off = 32; off; off >>= 1) t1 += __shfl_xor(t1, off, 64);
  if ((tid & 63) == 0) sm4[tid >> 6] = t1;
  __syncthreads();
  if (tid == 0) atomicAdd(t1g, sm4[0] + sm4[1] + sm4[2] + sm4[3]);
}

// ---------------- scalar reductions ----------------

__global__ __launch_bounds__(256) void k_stats(const float* __restrict__ mask, const float* __restrict__ rowV1,
                                               float* __restrict__ acc3) {
  __shared__ float sm[4];
  const int tid = threadIdx.x;
  float msum = 0.f, slat = 0.f;
  for (int n = blockIdx.x * 256 + tid; n < NTOK; n += gridDim.x * 256) {
    const float mk = mask[n];
    msum += mk;
    slat = fmaf(mk, 2.0f - 2.0f * rowV1[n], slat);
  }
  msum = block_reduce4(msum, sm, tid);
  slat = block_reduce4(slat, sm, tid);
  if (tid == 0) {
    atomicAdd(&acc3[0], msum);
    atomicAdd(&acc3[1], slat);
  }
}

__global__ __launch_bounds__(256) void k_final(const float* __restrict__ avgp, const float* __restrict__ t1g,
                                               const float* __restrict__ acc3, float* __restrict__ out3) {
  __shared__ float sm[4];
  const int tid = threadIdx.x;
  const float msum = acc3[0];
  float ae = 0.f;
  for (int k2 = tid; k2 < KCB; k2 += 256) {
    const float a = avgp[k2] / msum;
    ae += a * __logf(a + 1e-5f);
  }
  ae = block_reduce4(ae, sm, tid);
  if (tid == 0) {
    const float sample_entropy = -t1g[0] / msum;  // slogz folded analytically
    const float lat = acc3[1] / (msum + 1e-6f);
    out3[0] = lat;
    out3[1] = lat;
    out3[2] = sample_entropy + ae;
  }
}

// ---------------- launcher ----------------

extern "C" void kernel_launch(void* const* d_in, const int* in_sizes, int n_in,
                              void* d_out, int out_size, void* d_ws, size_t ws_size,
                              hipStream_t stream) {
  const float* x = (const float*)d_in[0];
  const float* mask = (const float*)d_in[1];
  const float* cb = (const float*)d_in[2];

  float* out = (float*)d_out;
  float* outQ = out;
  float* out3 = out + (size_t)NTOK * DIMD;
  float* outCnt = out3 + 3;
  float* outEnc = outCnt + KCB;

  // bf16-split x lives in the quantized output region until k_gather overwrites it
  u16* xh = (u16*)outQ;
  u16* xl = xh + (size_t)NTOK * DIMD;

  float* ws = (float*)d_ws;
  float* rowV1 = ws;                           // N
  float* rowZ = ws + (size_t)NTOK;             // N
  int* rowIdx = (int*)(ws + 2 * (size_t)NTOK); // N
  float* avgp = ws + 3 * (size_t)NTOK;         // K
  float* t1g = avgp + KCB;                     // 1
  float* acc3 = t1g + 1;                       // 3
  u16* cbh = (u16*)(ws + 3 * (size_t)NTOK + KCB + 8);
  u16* cbl = cbh + (size_t)KCB * DIMD;

  k_zero<<<(KCB + 255) / 256, 256, 0, stream>>>(avgp, t1g, acc3, outCnt);
  k_prepx<<<(NTOK * 64) / 256, 256, 0, stream>>>(x, mask, xh, xl);
  k_splitcb<<<(KCB * 64) / 256, 256, 0, stream>>>(cb, cbh, cbl);
  k_pass1<<<NTOK / 128, 256, 0, stream>>>(xh, xl, cbh, cbl, rowV1, rowZ, rowIdx);
  k_pass2<<<NTOK / 128, 256, 0, stream>>>(xh, xl, cbh, cbl, mask, rowV1, rowZ, avgp, t1g);
  k_stats<<<64, 256, 0, stream>>>(mask, rowV1, acc3);
  // gather runs after pass2 (outQ aliases xh/xl)
  k_gather<<<(NTOK * 32) / 256, 256, 0, stream>>>(cb, mask, rowIdx, outQ, outCnt, outEnc);
  k_final<<<1, 256, 0, stream>>>(avgp, t1g, acc3, out3);
}

// Round 8
// 226.131 us; speedup vs baseline: 2.1163x; 1.1810x over previous
//
#include <hip/hip_runtime.h>
#include <math.h>

#define NTOK 65536
#define DIMD 128
#define KCB  2048

typedef unsigned short u16;
typedef __attribute__((ext_vector_type(8))) unsigned short u16x8;
typedef __attribute__((ext_vector_type(8))) __bf16 bf16x8;
typedef __attribute__((ext_vector_type(4))) float f32x4;

union U8 { u16x8 u; bf16x8 b; };

__device__ __forceinline__ u16 f2bf(float f) {
  union { float f; unsigned u; } c; c.f = f;
  unsigned r = c.u + 0x7FFFu + ((c.u >> 16) & 1u);
  return (u16)(r >> 16);
}
__device__ __forceinline__ float bf2f(u16 h) {
  union { unsigned u; float f; } c; c.u = ((unsigned)h) << 16;
  return c.f;
}

__device__ __forceinline__ float block_reduce4(float v, volatile float* sm, int tid) {
  #pragma unroll
  for (int off = 32; off; off >>= 1) v += __shfl_xor(v, off, 64);
  __syncthreads();
  if ((tid & 63) == 0) sm[tid >> 6] = v;
  __syncthreads();
  float r = sm[0] + sm[1] + sm[2] + sm[3];
  __syncthreads();
  return r;
}

// linear tile staging: thread tid covers bytes [tid*16 + i*4096]; dest mirrors source
__device__ __forceinline__ void stage8(const char* srcLane, char* ldsWaveBase) {
  #pragma unroll
  for (int i = 0; i < 8; ++i)
    __builtin_amdgcn_global_load_lds((const __attribute__((address_space(1))) void*)(srcLane + i * 4096),
                                     (__attribute__((address_space(3))) void*)(ldsWaveBase + i * 4096), 16, 0, 0);
}
__device__ __forceinline__ void stage4(const char* srcLane, char* ldsWaveBase) {
  #pragma unroll
  for (int i = 0; i < 4; ++i)
    __builtin_amdgcn_global_load_lds((const __attribute__((address_space(1))) void*)(srcLane + i * 4096),
                                     (__attribute__((address_space(3))) void*)(ldsWaveBase + i * 4096), 16, 0, 0);
}

// ---------------- small kernels ----------------

__global__ __launch_bounds__(256) void k_zero(float* __restrict__ avgp, float* __restrict__ t1,
                                              float* __restrict__ acc3, float* __restrict__ cnt) {
  const int i = blockIdx.x * 256 + threadIdx.x;
  if (i < KCB) { avgp[i] = 0.0f; cnt[i] = 0.0f; }
  if (i == 0) { t1[0] = 0.0f; acc3[0] = 0.0f; acc3[1] = 0.0f; acc3[2] = 0.0f; }
}

// normalize rows of x -> bf16 split halves (one wave per row)
__global__ __launch_bounds__(256) void k_prepx(const float* __restrict__ x, const float* __restrict__ mask,
                                               u16* __restrict__ xh, u16* __restrict__ xl) {
  const int wid = (blockIdx.x * 256 + threadIdx.x) >> 6;
  const int lane = threadIdx.x & 63;
  if (wid >= NTOK) return;
  const float add = (1.0f - mask[wid]) * 1e-6f;
  const float2 v = *(const float2*)(x + (size_t)wid * DIMD + lane * 2);
  const float a0 = v.x + add, a1 = v.y + add;
  float ss = a0 * a0 + a1 * a1;
  #pragma unroll
  for (int off = 32; off; off >>= 1) ss += __shfl_xor(ss, off, 64);
  const float sc = 1.0f / fmaxf(sqrtf(ss), 1e-6f);
  const float f0 = a0 * sc, f1 = a1 * sc;
  const u16 h0 = f2bf(f0), h1 = f2bf(f1);
  const u16 g0 = f2bf(f0 - bf2f(h0)), g1 = f2bf(f1 - bf2f(h1));
  union { u16 s[2]; unsigned u; } wh, wl;
  wh.s[0] = h0; wh.s[1] = h1; wl.s[0] = g0; wl.s[1] = g1;
  *(unsigned*)(xh + (size_t)wid * DIMD + lane * 2) = wh.u;
  *(unsigned*)(xl + (size_t)wid * DIMD + lane * 2) = wl.u;
}

// pack codebook to bf16 H+L in MFMA-fragment order, 64-code tiles:
// tile T in [0,32): bytes [T*32768, +16384) = H frags, [+16384, +32768) = L frags
// frag f = ks*4+nf in [0,16): 64 lanes x 16B; code c = T*64+nf*16+(lane&15), dims d = ks*32+(lane>>4)*8..+8
__global__ __launch_bounds__(256) void k_packcb(const float* __restrict__ cb, u16* __restrict__ cbp) {
  const int gid = blockIdx.x * 256 + threadIdx.x;
  if (gid >= 32768) return;
  const int lane = gid & 63;
  const int f = (gid >> 6) & 15;
  const int T = gid >> 10;
  const int ks = f >> 2, nf = f & 3;
  const int hi = lane >> 4, l15 = lane & 15;
  const int c = T * 64 + nf * 16 + l15;
  const int d0 = ks * 32 + hi * 8;
  const float4 v0 = *(const float4*)(cb + (size_t)c * DIMD + d0);
  const float4 v1 = *(const float4*)(cb + (size_t)c * DIMD + d0 + 4);
  const float e[8] = {v0.x, v0.y, v0.z, v0.w, v1.x, v1.y, v1.z, v1.w};
  union { u16 s[8]; u16x8 u; } oh, ol;
  #pragma unroll
  for (int i = 0; i < 8; ++i) {
    const u16 h = f2bf(e[i]);
    oh.s[i] = h;
    ol.s[i] = f2bf(e[i] - bf2f(h));
  }
  u16* tile = cbp + (size_t)T * 16384;
  *(u16x8*)(tile + (f * 64 + lane) * 8) = oh.u;
  *(u16x8*)(tile + 8192 + (f * 64 + lane) * 8) = ol.u;
}

__global__ __launch_bounds__(256) void k_gather(const float* __restrict__ cb, const float* __restrict__ mask,
                                                const int* __restrict__ rowIdx, float* __restrict__ outQ,
                                                float* __restrict__ outCnt, float* __restrict__ outEnc) {
  const int g = blockIdx.x * 256 + threadIdx.x;
  const int row = g >> 5, l = g & 31;
  if (row >= NTOK) return;
  const int idx = rowIdx[row];
  const float4 v = *(const float4*)(cb + (size_t)idx * DIMD + l * 4);
  *(float4*)(outQ + (size_t)row * DIMD + l * 4) = v;
  if (l == 0) {
    atomicAdd(&outCnt[idx], mask[row]);
    outEnc[row] = (float)idx;
  }
}

// ---------------- MFMA pass 1 (split precision): per-row max / argmax / Z ----------------

__global__ __launch_bounds__(256, 2) void k_pass1(const u16* __restrict__ xh, const u16* __restrict__ xl,
                                                  const u16* __restrict__ cbp,
                                                  float* __restrict__ rowV1, float* __restrict__ rowZ,
                                                  int* __restrict__ rowIdx) {
  __shared__ __align__(16) char Bsmem[65536];  // 2 x (16KB H + 16KB L)
  const int tid = threadIdx.x;
  const int lane = tid & 63, w = tid >> 6;
  const int l15 = lane & 15, hi = lane >> 4;
  const int row0 = blockIdx.x * 128;
  const char* src = (const char*)cbp;

  U8 Ah[2][4], Al[2][4];
  #pragma unroll
  for (int mf = 0; mf < 2; ++mf) {
    const size_t arow = (size_t)(row0 + w * 32 + mf * 16 + l15);
    #pragma unroll
    for (int ks = 0; ks < 4; ++ks) {
      Ah[mf][ks].u = *(const u16x8*)(xh + arow * DIMD + ks * 32 + hi * 8);
      Al[mf][ks].u = *(const u16x8*)(xl + arow * DIMD + ks * 32 + hi * 8);
    }
  }

  float v1[8], rs[8];
  int k1[8];
  #pragma unroll
  for (int r = 0; r < 8; ++r) { v1[r] = -1e30f; rs[r] = 0.0f; k1[r] = 0; }

  stage8(src + 0 * 32768 + tid * 16, Bsmem + 0 * 32768 + w * 1024);
  stage8(src + 1 * 32768 + tid * 16, Bsmem + 1 * 32768 + w * 1024);

  for (int t = 0; t < 32; ++t) {
    const int b = t & 1;
    if (t < 30) asm volatile("s_waitcnt vmcnt(8)" ::: "memory");
    else        asm volatile("s_waitcnt vmcnt(0)" ::: "memory");
    __builtin_amdgcn_sched_barrier(0);
    __builtin_amdgcn_s_barrier();
    __builtin_amdgcn_sched_barrier(0);

    const char* base = Bsmem + b * 32768 + lane * 16;
    f32x4 acc[2][4];
    #pragma unroll
    for (int m = 0; m < 2; ++m)
      #pragma unroll
      for (int nf = 0; nf < 4; ++nf) acc[m][nf] = (f32x4){0.f, 0.f, 0.f, 0.f};

    __builtin_amdgcn_s_setprio(1);
    #pragma unroll
    for (int ks = 0; ks < 4; ++ks) {
      #pragma unroll
      for (int nf = 0; nf < 4; ++nf) {
        U8 bh, bl;
        bh.u = *(const u16x8*)(base + ((ks * 4 + nf) << 10));
        bl.u = *(const u16x8*)(base + 16384 + ((ks * 4 + nf) << 10));
        acc[0][nf] = __builtin_amdgcn_mfma_f32_16x16x32_bf16(Ah[0][ks].b, bh.b, acc[0][nf], 0, 0, 0);
        acc[1][nf] = __builtin_amdgcn_mfma_f32_16x16x32_bf16(Ah[1][ks].b, bh.b, acc[1][nf], 0, 0, 0);
        acc[0][nf] = __builtin_amdgcn_mfma_f32_16x16x32_bf16(Al[0][ks].b, bh.b, acc[0][nf], 0, 0, 0);
        acc[1][nf] = __builtin_amdgcn_mfma_f32_16x16x32_bf16(Al[1][ks].b, bh.b, acc[1][nf], 0, 0, 0);
        acc[0][nf] = __builtin_amdgcn_mfma_f32_16x16x32_bf16(Ah[0][ks].b, bl.b, acc[0][nf], 0, 0, 0);
        acc[1][nf] = __builtin_amdgcn_mfma_f32_16x16x32_bf16(Ah[1][ks].b, bl.b, acc[1][nf], 0, 0, 0);
      }
    }
    __builtin_amdgcn_s_setprio(0);
    asm volatile("s_waitcnt lgkmcnt(0)" ::: "memory");
    __builtin_amdgcn_sched_barrier(0);
    __builtin_amdgcn_s_barrier();
    __builtin_amdgcn_sched_barrier(0);
    if (t < 30)
      stage8(src + (size_t)(t + 2) * 32768 + tid * 16, Bsmem + b * 32768 + w * 1024);

    // epilogue (registers only) overlaps the prefetch
    const int colbase = t * 64 + l15;
    #pragma unroll
    for (int m = 0; m < 2; ++m)
      #pragma unroll
      for (int rg = 0; rg < 4; ++rg) {
        const int r = m * 4 + rg;
        float vv1 = v1[r];
        int kk1 = k1[r];
        const float mold = vv1;
        const float x0 = acc[m][0][rg], x1 = acc[m][1][rg];
        const float x2 = acc[m][2][rg], x3 = acc[m][3][rg];
        if (x0 > vv1) { vv1 = x0; kk1 = colbase; }
        if (x1 > vv1) { vv1 = x1; kk1 = colbase + 16; }
        if (x2 > vv1) { vv1 = x2; kk1 = colbase + 32; }
        if (x3 > vv1) { vv1 = x3; kk1 = colbase + 48; }
        const float mx = fmaxf(fmaxf(x0, x1), fmaxf(x2, x3));
        float z = rs[r];
        if (__any(vv1 > mold)) z *= __expf(200.f * (mold - vv1));
        if (__any(mx - vv1 > -0.125f)) {
          z += __expf(200.f * (x0 - vv1));
          z += __expf(200.f * (x1 - vv1));
          z += __expf(200.f * (x2 - vv1));
          z += __expf(200.f * (x3 - vv1));
        }
        v1[r] = vv1; k1[r] = kk1; rs[r] = z;
      }
  }

  // cross-lane merge within each 16-lane group
  #pragma unroll
  for (int m = 0; m < 2; ++m)
    #pragma unroll
    for (int rg = 0; rg < 4; ++rg) {
      const int r = m * 4 + rg;
      float a1 = v1[r], az = rs[r];
      int ak = k1[r];
      #pragma unroll
      for (int off = 1; off <= 8; off <<= 1) {
        const float o1 = __shfl_xor(a1, off, 64);
        const float oz = __shfl_xor(az, off, 64);
        const int okk = __shfl_xor(ak, off, 64);
        const float nm = fmaxf(a1, o1);
        az = az * __expf((a1 - nm) * 200.f) + oz * __expf((o1 - nm) * 200.f);
        const bool take = (o1 > a1) || (o1 == a1 && okk < ak);
        ak = take ? okk : ak;
        a1 = nm;
      }
      if (l15 == 0) {
        const int row = row0 + w * 32 + m * 16 + hi * 4 + rg;
        rowV1[row] = a1; rowZ[row] = az; rowIdx[row] = ak;
      }
    }
}

// ---------------- MFMA pass 2 (plain bf16): avg_probs column sums + sample-entropy ----------------

__global__ __launch_bounds__(256, 2) void k_pass2(const u16* __restrict__ xh, const u16* __restrict__ cbp,
                                                  const float* __restrict__ mask, const float* __restrict__ rowV1,
                                                  const float* __restrict__ rowZ, float* __restrict__ avgp,
                                                  float* __restrict__ t1g) {
  __shared__ __align__(16) char Bsmem[32768];  // 2 x 16KB H tiles
  __shared__ float ap[KCB];
  __shared__ float sm4[4];
  const int tid = threadIdx.x;
  const int lane = tid & 63, w = tid >> 6;
  const int l15 = lane & 15, hi = lane >> 4;
  const int row0 = blockIdx.x * 128;
  const char* src = (const char*)cbp;

  for (int i = tid; i < KCB; i += 256) ap[i] = 0.0f;

  U8 Ah[2][4];
  #pragma unroll
  for (int mf = 0; mf < 2; ++mf) {
    const size_t arow = (size_t)(row0 + w * 32 + mf * 16 + l15);
    #pragma unroll
    for (int ks = 0; ks < 4; ++ks)
      Ah[mf][ks].u = *(const u16x8*)(xh + arow * DIMD + ks * 32 + hi * 8);
  }

  // offr = log(mask/Z) - 200*max => p_masked = exp(200*s + offr); t1' = sum p*u'
  float offr[8];
  #pragma unroll
  for (int m = 0; m < 2; ++m)
    #pragma unroll
    for (int rg = 0; rg < 4; ++rg) {
      const int r = m * 4 + rg;
      const int row = row0 + w * 32 + m * 16 + hi * 4 + rg;
      const float zim = mask[row] / rowZ[row];
      const float lz = (zim > 0.0f) ? __logf(zim) : -1e30f;
      offr[r] = lz - 200.f * rowV1[row];
    }
  float t1 = 0.0f;

  stage4(src + 0 * 32768 + tid * 16, Bsmem + 0 * 16384 + w * 1024);
  stage4(src + 1 * 32768 + tid * 16, Bsmem + 1 * 16384 + w * 1024);

  // make ap[] zeroing visible before any wave's epilogue atomics
  __builtin_amdgcn_s_barrier();

  for (int t = 0; t < 32; ++t) {
    const int b = t & 1;
    if (t < 30) asm volatile("s_waitcnt vmcnt(4)" ::: "memory");
    else        asm volatile("s_waitcnt vmcnt(0)" ::: "memory");
    __builtin_amdgcn_sched_barrier(0);
    __builtin_amdgcn_s_barrier();
    __builtin_amdgcn_sched_barrier(0);

    const char* base = Bsmem + b * 16384 + lane * 16;
    f32x4 acc[2][4];
    #pragma unroll
    for (int m = 0; m < 2; ++m)
      #pragma unroll
      for (int nf = 0; nf < 4; ++nf) acc[m][nf] = (f32x4){0.f, 0.f, 0.f, 0.f};

    __builtin_amdgcn_s_setprio(1);
    #pragma unroll
    for (int ks = 0; ks < 4; ++ks) {
      #pragma unroll
      for (int nf = 0; nf < 4; ++nf) {
        U8 bb;
        bb.u = *(const u16x8*)(base + ((ks * 4 + nf) << 10));
        acc[0][nf] = __builtin_amdgcn_mfma_f32_16x16x32_bf16(Ah[0][ks].b, bb.b, acc[0][nf], 0, 0, 0);
        acc[1][nf] = __builtin_amdgcn_mfma_f32_16x16x32_bf16(Ah[1][ks].b, bb.b, acc[1][nf], 0, 0, 0);
      }
    }
    __builtin_amdgcn_s_setprio(0);
    asm volatile("s_waitcnt lgkmcnt(0)" ::: "memory");
    __builtin_amdgcn_sched_barrier(0);
    __builtin_amdgcn_s_barrier();
    __builtin_amdgcn_sched_barrier(0);
    if (t < 30)
      stage4(src + (size_t)(t + 2) * 32768 + tid * 16, Bsmem + b * 16384 + w * 1024);

    float colsum[4];
    #pragma unroll
    for (int nf = 0; nf < 4; ++nf) colsum[nf] = 0.0f;
    #pragma unroll
    for (int m = 0; m < 2; ++m)
      #pragma unroll
      for (int rg = 0; rg < 4; ++rg) {
        const int r = m * 4 + rg;
        float u_[4];
        float umx = -1e30f;
        #pragma unroll
        for (int nf = 0; nf < 4; ++nf) {
          u_[nf] = fmaf(acc[m][nf][rg], 200.f, offr[r]);
          umx = fmaxf(umx, u_[nf]);
        }
        if (__any(umx > -25.f)) {
          #pragma unroll
          for (int nf = 0; nf < 4; ++nf) {
            const float p = __expf(u_[nf]);
            colsum[nf] += p;
            t1 = fmaf(p, u_[nf], t1);
          }
        }
      }
    #pragma unroll
    for (int nf = 0; nf < 4; ++nf) {
      colsum[nf] += __shfl_xor(colsum[nf], 16, 64);
      colsum[nf] += __shfl_xor(colsum[nf], 32, 64);
    }
    if (lane < 16) {
      #pragma unroll
      for (int nf = 0; nf < 4; ++nf)
        atomicAdd(&ap[t * 64 + nf * 16 + lane], colsum[nf]);
    }
  }

  __syncthreads();
  for (int i = tid; i < KCB; i += 256) atomicAdd(&avgp[i], ap[i]);
  #pragma unroll
  for (int off = 32; off; off >>= 1) t1 += __shfl_xor(t1, off, 64);
  if ((tid & 63) == 0) sm4[tid >> 6] = t1;
  __syncthreads();
  if (tid == 0) atomicAdd(t1g, sm4[0] + sm4[1] + sm4[2] + sm4[3]);
}

// ---------------- scalar reductions ----------------

__global__ __launch_bounds__(256) void k_stats(const float* __restrict__ mask, const float* __restrict__ rowV1,
                                               float* __restrict__ acc3) {
  __shared__ float sm[4];
  const int tid = threadIdx.x;
  float msum = 0.f, slat = 0.f;
  for (int n = blockIdx.x * 256 + tid; n < NTOK; n += gridDim.x * 256) {
    const float mk = mask[n];
    msum += mk;
    slat = fmaf(mk, 2.0f - 2.0f * rowV1[n], slat);
  }
  msum = block_reduce4(msum, sm, tid);
  slat = block_reduce4(slat, sm, tid);
  if (tid == 0) {
    atomicAdd(&acc3[0], msum);
    atomicAdd(&acc3[1], slat);
  }
}

__global__ __launch_bounds__(256) void k_final(const float* __restrict__ avgp, const float* __restrict__ t1g,
                                               const float* __restrict__ acc3, float* __restrict__ out3) {
  __shared__ float sm[4];
  const int tid = threadIdx.x;
  const float msum = acc3[0];
  float ae = 0.f;
  for (int k2 = tid; k2 < KCB; k2 += 256) {
    const float a = avgp[k2] / msum;
    ae += a * __logf(a + 1e-5f);
  }
  ae = block_reduce4(ae, sm, tid);
  if (tid == 0) {
    const float sample_entropy = -t1g[0] / msum;  // slogz folded analytically
    const float lat = acc3[1] / (msum + 1e-6f);
    out3[0] = lat;
    out3[1] = lat;
    out3[2] = sample_entropy + ae;
  }
}

// ---------------- launcher ----------------

extern "C" void kernel_launch(void* const* d_in, const int* in_sizes, int n_in,
                              void* d_out, int out_size, void* d_ws, size_t ws_size,
                              hipStream_t stream) {
  const float* x = (const float*)d_in[0];
  const float* mask = (const float*)d_in[1];
  const float* cb = (const float*)d_in[2];

  float* out = (float*)d_out;
  float* outQ = out;
  float* out3 = out + (size_t)NTOK * DIMD;
  float* outCnt = out3 + 3;
  float* outEnc = outCnt + KCB;

  // bf16-split x lives in the quantized output region until k_gather overwrites it
  u16* xh = (u16*)outQ;
  u16* xl = xh + (size_t)NTOK * DIMD;

  float* ws = (float*)d_ws;
  float* rowV1 = ws;                           // N
  float* rowZ = ws + (size_t)NTOK;             // N
  int* rowIdx = (int*)(ws + 2 * (size_t)NTOK); // N
  float* avgp = ws + 3 * (size_t)NTOK;         // K
  float* t1g = avgp + KCB;                     // 1
  float* acc3 = t1g + 1;                       // 3
  u16* cbp = (u16*)(ws + 3 * (size_t)NTOK + KCB + 8);  // K*D*2 u16 fragment-packed H+L

  k_zero<<<(KCB + 255) / 256, 256, 0, stream>>>(avgp, t1g, acc3, outCnt);
  k_prepx<<<(NTOK * 64) / 256, 256, 0, stream>>>(x, mask, xh, xl);
  k_packcb<<<32768 / 256, 256, 0, stream>>>(cb, cbp);
  k_pass1<<<NTOK / 128, 256, 0, stream>>>(xh, xl, cbp, rowV1, rowZ, rowIdx);
  k_pass2<<<NTOK / 128, 256, 0, stream>>>(xh, cbp, mask, rowV1, rowZ, avgp, t1g);
  k_stats<<<64, 256, 0, stream>>>(mask, rowV1, acc3);
  // gather runs after pass2 (outQ aliases xh/xl)
  k_gather<<<(NTOK * 32) / 256, 256, 0, stream>>>(cb, mask, rowIdx, outQ, outCnt, outEnc);
  k_final<<<1, 256, 0, stream>>>(avgp, t1g, acc3, out3);
}